// Round 2
// baseline (676.942 us; speedup 1.0000x reference)
//
#include <hip/hip_runtime.h>
#include <hip/hip_bf16.h>

#define Bn 8
#define Hn 128
#define Wn 128
#define Cn 192
#define Gn 6
#define GCn 32
#define NPIX (Bn*Hn*Wn)   // 131072

typedef __attribute__((ext_vector_type(8))) short v8s;
typedef __attribute__((ext_vector_type(4))) float v4f;
typedef __hip_bfloat16 bf16;

__device__ __forceinline__ float b2f(bf16 v){ return __bfloat162float(v); }

// ---------------- fp32 -> bf16 conversion (8 elems/thread) ----------------
__global__ __launch_bounds__(256) void cvt_bf16(const float* __restrict__ in,
                                                bf16* __restrict__ out, long n)
{
    long base = ((long)blockIdx.x*256 + threadIdx.x)*8;
    if (base >= n) return;
    float v[8];
    *(float4*)(v)   = *(const float4*)(in + base);
    *(float4*)(v+4) = *(const float4*)(in + base + 4);
    bf16 o[8];
    #pragma unroll
    for (int j=0;j<8;j++) o[j] = __float2bfloat16(v[j]);
    *(uint4*)(out + base) = *(uint4*)o;
}

// ---------------- weight swizzle (fp32 in) into MFMA B-fragment order ----------------
// frag[nt(12)][ks(6)][lane(64)][j(8)]  element = W[k][n]
//   k = ks*32 + (lane>>4)*8 + j ,  n = nt*16 + (lane&15) ; n>=N -> 0
__global__ __launch_bounds__(256) void swizzle_w(const float* __restrict__ w,
                                                 bf16* __restrict__ out, int N)
{
    int idx = blockIdx.x*256 + threadIdx.x;        // < 36864
    int j = idx & 7, lane = (idx>>3)&63, ks = (idx>>9)%6, nt = idx/3072;
    int k = ks*32 + ((lane>>4)<<3) + j;
    int n = (nt<<4) + (lane&15);
    out[idx] = (n < N) ? __float2bfloat16(w[k*N + n]) : __float2bfloat16(0.0f);
}

// concat [w_off(192x108) | w_mask(192x54)] -> padded 192 cols; also concat fp32 bias
__global__ __launch_bounds__(256) void swizzle_om(const float* __restrict__ woff,
        const float* __restrict__ wmask, const float* __restrict__ boff,
        const float* __restrict__ bmask, bf16* __restrict__ out, float* __restrict__ biascat)
{
    int idx = blockIdx.x*256 + threadIdx.x;
    if (idx < 192) {
        float bv = 0.0f;
        if (idx < 108) bv = boff[idx];
        else if (idx < 162) bv = bmask[idx-108];
        biascat[idx] = bv;
    }
    int j = idx & 7, lane = (idx>>3)&63, ks = (idx>>9)%6, nt = idx/3072;
    int k = ks*32 + ((lane>>4)<<3) + j;
    int n = (nt<<4) + (lane&15);
    float v = 0.0f;
    if (n < 108)      v = woff[k*108 + n];
    else if (n < 162) v = wmask[k*54 + (n-108)];
    out[idx] = __float2bfloat16(v);
}

// ---------------- shared MFMA GEMM: [M=131072 x 192] @ [192 x <=192] ----------------
// blockIdx.y selects 96-col half (wfrag offset 6*6*64 v8s). LDS 36864B -> 4 blocks/CU.
__device__ __forceinline__ void store_out(bf16* p, float v){ *p = __float2bfloat16(v); }
__device__ __forceinline__ void store_out(float* p, float v){ *p = v; }

template<typename OutT>
__global__ __launch_bounds__(256,4) void gemm6(const bf16* __restrict__ A,
        const v8s* __restrict__ wfrag, const float* __restrict__ bias,
        OutT* __restrict__ Cmat, int Nreal, int Nstride)
{
    __shared__ v8s lds[6*6*64];
    const v8s* wsrc = wfrag + blockIdx.y*(6*6*64);
    int col0 = blockIdx.y*96;
    int tid = threadIdx.x;
    for (int i = tid; i < 6*6*64; i += 256) lds[i] = wsrc[i];
    __syncthreads();
    int wave = tid >> 6, lane = tid & 63;
    int q = lane >> 4, r = lane & 15;
    for (int mt = blockIdx.x; mt < NPIX/64; mt += gridDim.x) {
        int row_base = mt*64 + wave*16;
        const bf16* Ap = A + (size_t)(row_base + r)*Cn + q*8;
        v4f acc[6];
        #pragma unroll
        for (int nt=0;nt<6;nt++) acc[nt] = (v4f){0.f,0.f,0.f,0.f};
        #pragma unroll
        for (int ks=0; ks<6; ks++) {
            v8s av = *(const v8s*)(Ap + ks*32);
            #pragma unroll
            for (int nt=0;nt<6;nt++)
                acc[nt] = __builtin_amdgcn_mfma_f32_16x16x32_bf16(
                              av, lds[(nt*6+ks)*64 + lane], acc[nt], 0, 0, 0);
        }
        int orow = row_base + q*4;
        #pragma unroll
        for (int nt=0;nt<6;nt++) {
            int col = col0 + nt*16 + r;
            if (col < Nreal) {
                float bv = bias[col];
                #pragma unroll
                for (int i=0;i<4;i++)
                    store_out(&Cmat[(size_t)(orow+i)*Nstride + col], acc[nt][i] + bv);
            }
        }
    }
}

// ---------------- depthwise 3x3 + bias + SiLU (bf16 activations, fp32 weights) ----------------
__global__ __launch_bounds__(256) void dw_silu(const bf16* __restrict__ x,
        const float* __restrict__ wdw, const float* __restrict__ bdw, bf16* __restrict__ out)
{
    int idx = blockIdx.x*256 + threadIdx.x;      // NPIX*24 threads, 8 ch each
    int c8 = idx % 24; int pix = idx / 24;
    if (pix >= NPIX) return;
    int b = pix >> 14; int hw = pix & 16383; int h = hw >> 7, w = hw & 127;
    int cb = c8*8;
    float acc[8];
    #pragma unroll
    for (int j=0;j<8;j++) acc[j] = bdw[cb+j];
    #pragma unroll
    for (int dy=-1;dy<=1;dy++){
        int hh=h+dy; if ((unsigned)hh >= (unsigned)Hn) continue;
        #pragma unroll
        for (int dx=-1;dx<=1;dx++){
            int ww=w+dx; if ((unsigned)ww >= (unsigned)Wn) continue;
            const bf16* xp = x + ((size_t)((b<<14)+(hh<<7)+ww))*Cn + cb;
            const float* wp = wdw + ((dy+1)*3+(dx+1))*Cn + cb;
            bf16 xv[8]; float wv[8];
            *(uint4*)xv = *(const uint4*)xp;
            *(float4*)wv     = *(const float4*)wp;
            *(float4*)(wv+4) = *(const float4*)(wp+4);
            #pragma unroll
            for (int j=0;j<8;j++) acc[j] += b2f(xv[j])*wv[j];
        }
    }
    bf16 ov[8];
    #pragma unroll
    for (int j=0;j<8;j++){
        float v = acc[j];
        ov[j] = __float2bfloat16(v / (1.f + __expf(-v)));
    }
    *(uint4*)(out + (size_t)pix*Cn + cb) = *(uint4*)ov;
}

// ---------------- deformable sampling ----------------
// OM row (162 bf16): [0..107] offsets (g*18 + 2k + {h,w}), [108..161] mask logits (g*9+k)
__global__ __launch_bounds__(256) void deform_sample(const bf16* __restrict__ P,
        const bf16* __restrict__ OM, bf16* __restrict__ S)
{
    int idx = blockIdx.x*256 + threadIdx.x;      // NPIX*24 threads
    int c8 = idx % 24; int pix = idx / 24;
    if (pix >= NPIX) return;
    int b = pix >> 14; int hw = pix & 16383; int h = hw >> 7, w = hw & 127;
    int g = c8 >> 2, sub = c8 & 3;
    const bf16* om = OM + (size_t)pix*162;

    float att[9];
    float m = -1e30f;
    #pragma unroll
    for (int k=0;k<9;k++){ att[k] = b2f(om[108 + g*9 + k]); m = fmaxf(m, att[k]); }
    float ssum = 0.f;
    #pragma unroll
    for (int k=0;k<9;k++){ att[k] = __expf(att[k]-m); ssum += att[k]; }
    float inv = 1.f/ssum;

    float acc[8] = {0.f,0.f,0.f,0.f,0.f,0.f,0.f,0.f};
    const bf16* xb = P + (((size_t)b) << 14)*Cn + g*GCn + sub*8;
    #pragma unroll
    for (int k=0;k<9;k++){
        int dh = k/3 - 1, dwp = k%3 - 1;
        float ph = (float)(h + dh) + 0.1f*b2f(om[g*18 + 2*k]);
        float pw = (float)(w + dwp) + 0.1f*b2f(om[g*18 + 2*k + 1]);
        ph = fminf(fmaxf(ph, 0.f), 127.f);
        pw = fminf(fmaxf(pw, 0.f), 127.f);
        int hf = (int)ph, wf = (int)pw;
        float fh = ph - (float)hf, fw = pw - (float)wf;
        int hc = min(hf+1,127), wc = min(wf+1,127);
        float a = att[k]*inv;
        float w00=(1.f-fh)*(1.f-fw)*a, w01=(1.f-fh)*fw*a, w10=fh*(1.f-fw)*a, w11=fh*fw*a;
        const bf16* p00 = xb + (size_t)((hf<<7)+wf)*Cn;
        const bf16* p01 = xb + (size_t)((hf<<7)+wc)*Cn;
        const bf16* p10 = xb + (size_t)((hc<<7)+wf)*Cn;
        const bf16* p11 = xb + (size_t)((hc<<7)+wc)*Cn;
        bf16 v00[8], v01[8], v10[8], v11[8];
        *(uint4*)v00 = *(const uint4*)p00;
        *(uint4*)v01 = *(const uint4*)p01;
        *(uint4*)v10 = *(const uint4*)p10;
        *(uint4*)v11 = *(const uint4*)p11;
        #pragma unroll
        for (int j=0;j<8;j++)
            acc[j] += w00*b2f(v00[j]) + w01*b2f(v01[j]) + w10*b2f(v10[j]) + w11*b2f(v11[j]);
    }
    bf16 ov[8];
    #pragma unroll
    for (int j=0;j<8;j++) ov[j] = __float2bfloat16(acc[j]);
    *(uint4*)(S + (size_t)pix*Cn + g*GCn + sub*8) = *(uint4*)ov;
}

extern "C" void kernel_launch(void* const* d_in, const int* in_sizes, int n_in,
                              void* d_out, int out_size, void* d_ws, size_t ws_size,
                              hipStream_t stream)
{
    const float* x      = (const float*)d_in[0];
    const float* w_in   = (const float*)d_in[1];
    const float* b_in   = (const float*)d_in[2];
    const float* w_dw   = (const float*)d_in[3];
    const float* b_dw   = (const float*)d_in[4];
    const float* w_pw   = (const float*)d_in[5];
    const float* b_pw   = (const float*)d_in[6];
    const float* w_off  = (const float*)d_in[7];
    const float* b_off  = (const float*)d_in[8];
    const float* w_mask = (const float*)d_in[9];
    const float* b_mask = (const float*)d_in[10];
    const float* w_out  = (const float*)d_in[11];
    const float* b_out  = (const float*)d_in[12];
    float* out = (float*)d_out;

    char* ws = (char*)d_ws;
    size_t off = 0;
    auto carve = [&](size_t bytes)->char* {
        char* p = ws + off; off += (bytes + 255) & ~(size_t)255; return p; };
    bf16* XB  = (bf16*)carve((size_t)NPIX*Cn*2);   // bf16 x; later reused as X2
    bf16* P   = (bf16*)carve((size_t)NPIX*Cn*2);   // x_proj
    bf16* D   = (bf16*)carve((size_t)NPIX*Cn*2);   // dw out, later reused as sampled S
    bf16* OM  = (bf16*)carve((size_t)NPIX*162*2);  // offsets|mask logits
    bf16* wfI = (bf16*)carve(36864*2);
    bf16* wfP = (bf16*)carve(36864*2);
    bf16* wfO = (bf16*)carve(36864*2);
    bf16* wfM = (bf16*)carve(36864*2);
    float* bM = (float*)carve(192*4);

    dim3 blk(256);
    cvt_bf16<<<12288, blk, 0, stream>>>(x, XB, (long)NPIX*Cn);
    swizzle_w<<<144, blk, 0, stream>>>(w_in,  wfI, 192);
    swizzle_w<<<144, blk, 0, stream>>>(w_pw,  wfP, 192);
    swizzle_w<<<144, blk, 0, stream>>>(w_out, wfO, 192);
    swizzle_om<<<144, blk, 0, stream>>>(w_off, w_mask, b_off, b_mask, wfM, bM);

    dim3 ggrid(512, 2);
    gemm6<bf16><<<ggrid, blk, 0, stream>>>(XB, (const v8s*)wfI, b_in, P, 192, 192);

    dw_silu<<<12288, blk, 0, stream>>>(XB, w_dw, b_dw, D);

    // XB dead now; reuse as X2
    bf16* X2 = XB;
    gemm6<bf16><<<ggrid, blk, 0, stream>>>(D,  (const v8s*)wfP, b_pw, X2, 192, 192);
    gemm6<bf16><<<ggrid, blk, 0, stream>>>(X2, (const v8s*)wfM, bM,  OM, 162, 162);

    deform_sample<<<12288, blk, 0, stream>>>(P, OM, D);   // S overwrites D

    gemm6<float><<<ggrid, blk, 0, stream>>>(D, (const v8s*)wfO, b_out, out, 192, 192);
}

// Round 3
// 578.909 us; speedup vs baseline: 1.1693x; 1.1693x over previous
//
#include <hip/hip_runtime.h>
#include <hip/hip_bf16.h>

#define Bn 8
#define Hn 128
#define Wn 128
#define Cn 192
#define Gn 6
#define GCn 32
#define NPIX (Bn*Hn*Wn)   // 131072

typedef __attribute__((ext_vector_type(8))) short v8s;
typedef __attribute__((ext_vector_type(4))) float v4f;
typedef __hip_bfloat16 bf16;

__device__ __forceinline__ float b2f(bf16 v){ return __bfloat162float(v); }
__device__ __forceinline__ float lo16(unsigned u){ return __uint_as_float(u << 16); }
__device__ __forceinline__ float hi16(unsigned u){ return __uint_as_float(u & 0xffff0000u); }

// ---------------- fp32 -> bf16 conversion (8 elems/thread) ----------------
__global__ __launch_bounds__(256) void cvt_bf16(const float* __restrict__ in,
                                                bf16* __restrict__ out, long n)
{
    long base = ((long)blockIdx.x*256 + threadIdx.x)*8;
    if (base >= n) return;
    float v[8];
    *(float4*)(v)   = *(const float4*)(in + base);
    *(float4*)(v+4) = *(const float4*)(in + base + 4);
    bf16 o[8];
    #pragma unroll
    for (int j=0;j<8;j++) o[j] = __float2bfloat16(v[j]);
    *(uint4*)(out + base) = *(uint4*)o;
}

// ---------------- weight swizzle (fp32 in) into MFMA B-fragment order ----------------
// frag[nt(12)][ks(6)][lane(64)][j(8)]  element = W[k][n]
//   k = ks*32 + (lane>>4)*8 + j ,  n = nt*16 + (lane&15) ; n>=N -> 0
__global__ __launch_bounds__(256) void swizzle_w(const float* __restrict__ w,
                                                 bf16* __restrict__ out, int N)
{
    int idx = blockIdx.x*256 + threadIdx.x;        // < 36864
    int j = idx & 7, lane = (idx>>3)&63, ks = (idx>>9)%6, nt = idx/3072;
    int k = ks*32 + ((lane>>4)<<3) + j;
    int n = (nt<<4) + (lane&15);
    out[idx] = (n < N) ? __float2bfloat16(w[k*N + n]) : __float2bfloat16(0.0f);
}

// concat [w_off(192x108) | w_mask(192x54)] -> padded 192 cols; also concat fp32 bias
__global__ __launch_bounds__(256) void swizzle_om(const float* __restrict__ woff,
        const float* __restrict__ wmask, const float* __restrict__ boff,
        const float* __restrict__ bmask, bf16* __restrict__ out, float* __restrict__ biascat)
{
    int idx = blockIdx.x*256 + threadIdx.x;
    if (idx < 192) {
        float bv = 0.0f;
        if (idx < 108) bv = boff[idx];
        else if (idx < 162) bv = bmask[idx-108];
        biascat[idx] = bv;
    }
    int j = idx & 7, lane = (idx>>3)&63, ks = (idx>>9)%6, nt = idx/3072;
    int k = ks*32 + ((lane>>4)<<3) + j;
    int n = (nt<<4) + (lane&15);
    float v = 0.0f;
    if (n < 108)      v = woff[k*108 + n];
    else if (n < 162) v = wmask[k*54 + (n-108)];
    out[idx] = __float2bfloat16(v);
}

// ---------------- MFMA GEMM, B fully in registers: [131072 x 192] @ [192 x <=192] ----------------
// grid (512, 2); blockIdx.y selects 96-col half. 36 B-fragments/wave in VGPRs, no LDS.
__device__ __forceinline__ void store_out(bf16* p, float v){ *p = __float2bfloat16(v); }
__device__ __forceinline__ void store_out(float* p, float v){ *p = v; }

template<typename OutT>
__global__ __launch_bounds__(256, 2) void gemm6r(const bf16* __restrict__ A,
        const v8s* __restrict__ wfrag, const float* __restrict__ bias,
        OutT* __restrict__ Cmat, int Nreal, int Nstride)
{
    int tid = threadIdx.x;
    int wave = tid >> 6, lane = tid & 63;
    int q = lane >> 4, r = lane & 15;
    const v8s* wsrc = wfrag + blockIdx.y*(36*64) + lane;
    v8s breg[36];
    #pragma unroll
    for (int f=0; f<36; f++) breg[f] = wsrc[f*64];
    int col0 = blockIdx.y*96;
    float bv[6];
    #pragma unroll
    for (int nt=0; nt<6; nt++) {
        int col = col0 + nt*16 + r;
        bv[nt] = (col < Nreal) ? bias[col] : 0.0f;
    }
    const int MT = NPIX/64;   // 2048
    for (int mt = blockIdx.x; mt < MT; mt += gridDim.x) {
        const bf16* Ap = A + (size_t)(mt*64 + wave*16 + r)*Cn + q*8;
        v8s av[6];
        #pragma unroll
        for (int ks=0; ks<6; ks++) av[ks] = *(const v8s*)(Ap + ks*32);
        v4f acc[6];
        #pragma unroll
        for (int nt=0;nt<6;nt++) acc[nt] = (v4f){0.f,0.f,0.f,0.f};
        #pragma unroll
        for (int ks=0; ks<6; ks++)
            #pragma unroll
            for (int nt=0;nt<6;nt++)
                acc[nt] = __builtin_amdgcn_mfma_f32_16x16x32_bf16(
                              av[ks], breg[nt*6+ks], acc[nt], 0, 0, 0);
        int orow = mt*64 + wave*16 + q*4;
        #pragma unroll
        for (int nt=0;nt<6;nt++) {
            int col = col0 + nt*16 + r;
            if (col < Nreal) {
                #pragma unroll
                for (int i=0;i<4;i++)
                    store_out(&Cmat[(size_t)(orow+i)*Nstride + col], acc[nt][i] + bv[nt]);
            }
        }
    }
}

// ---------------- depthwise 3x3 + bias + SiLU, 32 ch/thread ----------------
__global__ __launch_bounds__(256) void dw_silu(const bf16* __restrict__ x,
        const bf16* __restrict__ wdwb, const float* __restrict__ bdw, bf16* __restrict__ out)
{
    int idx = blockIdx.x*256 + threadIdx.x;      // NPIX*6 threads, 32 ch each
    int c32 = idx % 6; int pix = idx / 6;
    int b = pix >> 14; int hw = pix & 16383; int h = hw >> 7, w = hw & 127;
    int cb = c32*32;
    float acc[32];
    #pragma unroll
    for (int cs=0;cs<8;cs++) *(float4*)(acc+cs*4) = *(const float4*)(bdw + cb + cs*4);
    #pragma unroll
    for (int dy=-1;dy<=1;dy++){
        int hh=h+dy; if ((unsigned)hh >= (unsigned)Hn) continue;
        #pragma unroll
        for (int dx=-1;dx<=1;dx++){
            int ww=w+dx; if ((unsigned)ww >= (unsigned)Wn) continue;
            const uint4* xp = (const uint4*)(x + ((size_t)((b<<14)+(hh<<7)+ww))*Cn + cb);
            const uint4* wp = (const uint4*)(wdwb + ((dy+1)*3+(dx+1))*Cn + cb);
            #pragma unroll
            for (int cs=0;cs<4;cs++){
                uint4 xu = xp[cs], wu = wp[cs];
                unsigned xa[4] = {xu.x,xu.y,xu.z,xu.w};
                unsigned wa[4] = {wu.x,wu.y,wu.z,wu.w};
                #pragma unroll
                for (int t=0;t<4;t++){
                    acc[cs*8+2*t]   += lo16(xa[t])*lo16(wa[t]);
                    acc[cs*8+2*t+1] += hi16(xa[t])*hi16(wa[t]);
                }
            }
        }
    }
    bf16 ov[32];
    #pragma unroll
    for (int j=0;j<32;j++){
        float v = acc[j];
        ov[j] = __float2bfloat16(v / (1.f + __expf(-v)));
    }
    uint4* op = (uint4*)(out + (size_t)pix*Cn + cb);
    #pragma unroll
    for (int cs=0;cs<4;cs++) op[cs] = ((uint4*)ov)[cs];
}

// ---------------- deformable sampling, one (pix,group) per thread ----------------
// OM row (162 bf16): [0..107] offsets (g*18 + 2k + {h,w}), [108..161] mask logits (g*9+k)
__global__ __launch_bounds__(256) void deform_sample(const bf16* __restrict__ P,
        const bf16* __restrict__ OM, bf16* __restrict__ S)
{
    int idx = blockIdx.x*256 + threadIdx.x;      // NPIX*6 threads
    int g = idx % 6; int pix = idx / 6;
    int b = pix >> 14; int hw = pix & 16383; int h = hw >> 7, w = hw & 127;
    const bf16* om = OM + (size_t)pix*162;
    const bf16* oml = om + 108 + g*9;
    const unsigned* ofp = (const unsigned*)(om + g*18);

    float att[9];
    float m = -1e30f;
    #pragma unroll
    for (int k=0;k<9;k++){ att[k] = b2f(oml[k]); m = fmaxf(m, att[k]); }
    float ssum = 0.f;
    #pragma unroll
    for (int k=0;k<9;k++){ att[k] = __expf(att[k]-m); ssum += att[k]; }
    float inv = 1.f/ssum;

    float acc[32];
    #pragma unroll
    for (int j=0;j<32;j++) acc[j] = 0.f;
    const bf16* xb = P + (((size_t)b) << 14)*Cn + g*GCn;
    #pragma unroll
    for (int k=0;k<9;k++){
        unsigned opair = ofp[k];
        float ph = (float)(h + k/3 - 1) + 0.1f*lo16(opair);
        float pw = (float)(w + k%3 - 1) + 0.1f*hi16(opair);
        ph = fminf(fmaxf(ph, 0.f), 127.f);
        pw = fminf(fmaxf(pw, 0.f), 127.f);
        int hf = (int)ph, wf = (int)pw;
        float fh = ph - (float)hf, fw = pw - (float)wf;
        int hc = min(hf+1,127), wc = min(wf+1,127);
        float a = att[k]*inv;
        float w00=(1.f-fh)*(1.f-fw)*a, w01=(1.f-fh)*fw*a, w10=fh*(1.f-fw)*a, w11=fh*fw*a;
        const uint4* p00 = (const uint4*)(xb + ((hf<<7)+wf)*Cn);
        const uint4* p01 = (const uint4*)(xb + ((hf<<7)+wc)*Cn);
        const uint4* p10 = (const uint4*)(xb + ((hc<<7)+wf)*Cn);
        const uint4* p11 = (const uint4*)(xb + ((hc<<7)+wc)*Cn);
        #pragma unroll
        for (int cs=0;cs<4;cs++){
            uint4 a00=p00[cs], a01=p01[cs], a10=p10[cs], a11=p11[cs];
            unsigned u00[4]={a00.x,a00.y,a00.z,a00.w};
            unsigned u01[4]={a01.x,a01.y,a01.z,a01.w};
            unsigned u10[4]={a10.x,a10.y,a10.z,a10.w};
            unsigned u11[4]={a11.x,a11.y,a11.z,a11.w};
            #pragma unroll
            for (int t=0;t<4;t++){
                acc[cs*8+2*t]   += w00*lo16(u00[t]) + w01*lo16(u01[t])
                                 + w10*lo16(u10[t]) + w11*lo16(u11[t]);
                acc[cs*8+2*t+1] += w00*hi16(u00[t]) + w01*hi16(u01[t])
                                 + w10*hi16(u10[t]) + w11*hi16(u11[t]);
            }
        }
    }
    bf16 ov[32];
    #pragma unroll
    for (int j=0;j<32;j++) ov[j] = __float2bfloat16(acc[j]);
    uint4* sp = (uint4*)(S + (size_t)pix*Cn + g*GCn);
    #pragma unroll
    for (int cs=0;cs<4;cs++) sp[cs] = ((uint4*)ov)[cs];
}

extern "C" void kernel_launch(void* const* d_in, const int* in_sizes, int n_in,
                              void* d_out, int out_size, void* d_ws, size_t ws_size,
                              hipStream_t stream)
{
    const float* x      = (const float*)d_in[0];
    const float* w_in   = (const float*)d_in[1];
    const float* b_in   = (const float*)d_in[2];
    const float* w_dw   = (const float*)d_in[3];
    const float* b_dw   = (const float*)d_in[4];
    const float* w_pw   = (const float*)d_in[5];
    const float* b_pw   = (const float*)d_in[6];
    const float* w_off  = (const float*)d_in[7];
    const float* b_off  = (const float*)d_in[8];
    const float* w_mask = (const float*)d_in[9];
    const float* b_mask = (const float*)d_in[10];
    const float* w_out  = (const float*)d_in[11];
    const float* b_out  = (const float*)d_in[12];
    float* out = (float*)d_out;

    char* ws = (char*)d_ws;
    size_t off = 0;
    auto carve = [&](size_t bytes)->char* {
        char* p = ws + off; off += (bytes + 255) & ~(size_t)255; return p; };
    bf16* XB  = (bf16*)carve((size_t)NPIX*Cn*2);   // bf16 x; later reused as X2
    bf16* P   = (bf16*)carve((size_t)NPIX*Cn*2);   // x_proj
    bf16* D   = (bf16*)carve((size_t)NPIX*Cn*2);   // dw out, later reused as sampled S
    bf16* OM  = (bf16*)carve((size_t)NPIX*162*2);  // offsets|mask logits
    bf16* wfI = (bf16*)carve(36864*2);
    bf16* wfP = (bf16*)carve(36864*2);
    bf16* wfO = (bf16*)carve(36864*2);
    bf16* wfM = (bf16*)carve(36864*2);
    float* bM = (float*)carve(192*4);
    bf16* WDW = (bf16*)carve(1728*2);

    dim3 blk(256);
    cvt_bf16<<<12288, blk, 0, stream>>>(x, XB, (long)NPIX*Cn);
    cvt_bf16<<<1,     blk, 0, stream>>>(w_dw, WDW, 1728);
    swizzle_w<<<144, blk, 0, stream>>>(w_in,  wfI, 192);
    swizzle_w<<<144, blk, 0, stream>>>(w_pw,  wfP, 192);
    swizzle_w<<<144, blk, 0, stream>>>(w_out, wfO, 192);
    swizzle_om<<<144, blk, 0, stream>>>(w_off, w_mask, b_off, b_mask, wfM, bM);

    dim3 ggrid(512, 2);
    gemm6r<bf16><<<ggrid, blk, 0, stream>>>(XB, (const v8s*)wfI, b_in, P, 192, 192);

    dw_silu<<<3072, blk, 0, stream>>>(XB, WDW, b_dw, D);

    // XB dead now; reuse as X2
    bf16* X2 = XB;
    gemm6r<bf16><<<ggrid, blk, 0, stream>>>(D,  (const v8s*)wfP, b_pw, X2, 192, 192);
    gemm6r<bf16><<<ggrid, blk, 0, stream>>>(X2, (const v8s*)wfM, bM,  OM, 162, 162);

    deform_sample<<<3072, blk, 0, stream>>>(P, OM, D);   // S overwrites D

    gemm6r<float><<<ggrid, blk, 0, stream>>>(D, (const v8s*)wfO, b_out, out, 192, 192);
}

// Round 4
// 485.152 us; speedup vs baseline: 1.3953x; 1.1933x over previous
//
#include <hip/hip_runtime.h>
#include <hip/hip_bf16.h>

#define Bn 8
#define Hn 128
#define Wn 128
#define Cn 192
#define Gn 6
#define GCn 32
#define NPIX (Bn*Hn*Wn)   // 131072

typedef __attribute__((ext_vector_type(8))) short v8s;
typedef __attribute__((ext_vector_type(4))) float v4f;
typedef __attribute__((ext_vector_type(2))) float v2f;
typedef __hip_bfloat16 bf16;

__device__ __forceinline__ float b2f(bf16 v){ return __bfloat162float(v); }
__device__ __forceinline__ float lo16(unsigned u){ return __uint_as_float(u << 16); }
__device__ __forceinline__ float hi16(unsigned u){ return __uint_as_float(u & 0xffff0000u); }
// bf16 pair (lo,hi) -> float2 ; consumed by v_pk_fma_f32
__device__ __forceinline__ v2f up2(unsigned u){
    return (v2f){ __uint_as_float(u << 16), __uint_as_float(u & 0xffff0000u) };
}

// ---------------- fp32 -> bf16 conversion (8 elems/thread) ----------------
__global__ __launch_bounds__(256) void cvt_bf16(const float* __restrict__ in,
                                                bf16* __restrict__ out, long n)
{
    long base = ((long)blockIdx.x*256 + threadIdx.x)*8;
    if (base >= n) return;
    float v[8];
    *(float4*)(v)   = *(const float4*)(in + base);
    *(float4*)(v+4) = *(const float4*)(in + base + 4);
    bf16 o[8];
    #pragma unroll
    for (int j=0;j<8;j++) o[j] = __float2bfloat16(v[j]);
    *(uint4*)(out + base) = *(uint4*)o;
}

// ---------------- weight swizzle (fp32 in) into MFMA B-fragment order ----------------
// frag[nt(12)][ks(6)][lane(64)][j(8)]  element = W[k][n]
//   k = ks*32 + (lane>>4)*8 + j ,  n = nt*16 + (lane&15) ; n>=N -> 0
__global__ __launch_bounds__(256) void swizzle_w(const float* __restrict__ w,
                                                 bf16* __restrict__ out, int N)
{
    int idx = blockIdx.x*256 + threadIdx.x;        // < 36864
    int j = idx & 7, lane = (idx>>3)&63, ks = (idx>>9)%6, nt = idx/3072;
    int k = ks*32 + ((lane>>4)<<3) + j;
    int n = (nt<<4) + (lane&15);
    out[idx] = (n < N) ? __float2bfloat16(w[k*N + n]) : __float2bfloat16(0.0f);
}

// concat [w_off(192x108) | w_mask(192x54)] -> padded 192 cols; also concat fp32 bias
__global__ __launch_bounds__(256) void swizzle_om(const float* __restrict__ woff,
        const float* __restrict__ wmask, const float* __restrict__ boff,
        const float* __restrict__ bmask, bf16* __restrict__ out, float* __restrict__ biascat)
{
    int idx = blockIdx.x*256 + threadIdx.x;
    if (idx < 192) {
        float bv = 0.0f;
        if (idx < 108) bv = boff[idx];
        else if (idx < 162) bv = bmask[idx-108];
        biascat[idx] = bv;
    }
    int j = idx & 7, lane = (idx>>3)&63, ks = (idx>>9)%6, nt = idx/3072;
    int k = ks*32 + ((lane>>4)<<3) + j;
    int n = (nt<<4) + (lane&15);
    float v = 0.0f;
    if (n < 108)      v = woff[k*108 + n];
    else if (n < 162) v = wmask[k*54 + (n-108)];
    out[idx] = __float2bfloat16(v);
}

// ---------------- MFMA GEMM, B fully in registers: [131072 x 192] @ [192 x <=192] ----------------
// grid (512, 2); blockIdx.y selects 96-col half. 36 B-fragments/wave in VGPRs, no LDS.
__device__ __forceinline__ void store_out(bf16* p, float v){ *p = __float2bfloat16(v); }
__device__ __forceinline__ void store_out(float* p, float v){ *p = v; }

template<typename OutT>
__global__ __launch_bounds__(256, 2) void gemm6r(const bf16* __restrict__ A,
        const v8s* __restrict__ wfrag, const float* __restrict__ bias,
        OutT* __restrict__ Cmat, int Nreal, int Nstride)
{
    int tid = threadIdx.x;
    int wave = tid >> 6, lane = tid & 63;
    int q = lane >> 4, r = lane & 15;
    const v8s* wsrc = wfrag + blockIdx.y*(36*64) + lane;
    v8s breg[36];
    #pragma unroll
    for (int f=0; f<36; f++) breg[f] = wsrc[f*64];
    int col0 = blockIdx.y*96;
    float bv[6];
    #pragma unroll
    for (int nt=0; nt<6; nt++) {
        int col = col0 + nt*16 + r;
        bv[nt] = (col < Nreal) ? bias[col] : 0.0f;
    }
    const int MT = NPIX/64;   // 2048
    for (int mt = blockIdx.x; mt < MT; mt += gridDim.x) {
        const bf16* Ap = A + (size_t)(mt*64 + wave*16 + r)*Cn + q*8;
        v8s av[6];
        #pragma unroll
        for (int ks=0; ks<6; ks++) av[ks] = *(const v8s*)(Ap + ks*32);
        v4f acc[6];
        #pragma unroll
        for (int nt=0;nt<6;nt++) acc[nt] = (v4f){0.f,0.f,0.f,0.f};
        #pragma unroll
        for (int ks=0; ks<6; ks++)
            #pragma unroll
            for (int nt=0;nt<6;nt++)
                acc[nt] = __builtin_amdgcn_mfma_f32_16x16x32_bf16(
                              av[ks], breg[nt*6+ks], acc[nt], 0, 0, 0);
        int orow = mt*64 + wave*16 + q*4;
        #pragma unroll
        for (int nt=0;nt<6;nt++) {
            int col = col0 + nt*16 + r;
            if (col < Nreal) {
                #pragma unroll
                for (int i=0;i<4;i++)
                    store_out(&Cmat[(size_t)(orow+i)*Nstride + col], acc[nt][i] + bv[nt]);
            }
        }
    }
}

// ---------------- depthwise 3x3 + bias + SiLU, 16 ch/thread, packed-f32 acc ----------------
__global__ __launch_bounds__(256, 4) void dw_silu(const bf16* __restrict__ x,
        const bf16* __restrict__ wdwb, const float* __restrict__ bdw, bf16* __restrict__ out)
{
    int idx = blockIdx.x*256 + threadIdx.x;      // NPIX*12 threads, 16 ch each
    int c16 = idx % 12; int pix = idx / 12;
    int b = pix >> 14; int hw = pix & 16383; int h = hw >> 7, w = hw & 127;
    int cb = c16*16;
    v2f acc2[8];
    #pragma unroll
    for (int j=0;j<8;j++) acc2[j] = (v2f){bdw[cb+2*j], bdw[cb+2*j+1]};
    #pragma unroll
    for (int dy=-1;dy<=1;dy++){
        int hh=h+dy; if ((unsigned)hh >= (unsigned)Hn) continue;
        #pragma unroll
        for (int dx=-1;dx<=1;dx++){
            int ww=w+dx; if ((unsigned)ww >= (unsigned)Wn) continue;
            const uint4* xp = (const uint4*)(x + ((size_t)((b<<14)+(hh<<7)+ww))*Cn + cb);
            const uint4* wp = (const uint4*)(wdwb + ((dy+1)*3+(dx+1))*Cn + cb);
            #pragma unroll
            for (int cs=0;cs<2;cs++){
                uint4 xu = xp[cs], wu = wp[cs];
                unsigned xa[4] = {xu.x,xu.y,xu.z,xu.w};
                unsigned wa[4] = {wu.x,wu.y,wu.z,wu.w};
                #pragma unroll
                for (int t=0;t<4;t++)
                    acc2[cs*4+t] += up2(xa[t]) * up2(wa[t]);
            }
        }
    }
    bf16 ov[16];
    #pragma unroll
    for (int j=0;j<8;j++){
        float v0 = acc2[j].x, v1 = acc2[j].y;
        ov[2*j]   = __float2bfloat16(v0 / (1.f + __expf(-v0)));
        ov[2*j+1] = __float2bfloat16(v1 / (1.f + __expf(-v1)));
    }
    uint4* op = (uint4*)(out + (size_t)pix*Cn + cb);
    op[0] = ((uint4*)ov)[0];
    op[1] = ((uint4*)ov)[1];
}

// ---------------- deformable sampling, 2 threads per (pix,group), 16 ch each ----------------
// OM row (162 bf16): [0..107] offsets (g*18 + 2k + {h,w}), [108..161] mask logits (g*9+k)
__global__ __launch_bounds__(256, 4) void deform_sample(const bf16* __restrict__ P,
        const bf16* __restrict__ OM, bf16* __restrict__ S)
{
    int idx = blockIdx.x*256 + threadIdx.x;      // NPIX*12 threads
    int half = idx & 1;
    int g = (idx >> 1) % 6;
    int pix = idx / 12;
    int b = pix >> 14; int hw = pix & 16383; int h = hw >> 7, w = hw & 127;
    const bf16* om = OM + (size_t)pix*162;
    const bf16* oml = om + 108 + g*9;
    const unsigned* ofp = (const unsigned*)(om + g*18);

    float att[9];
    float m = -1e30f;
    #pragma unroll
    for (int k=0;k<9;k++){ att[k] = b2f(oml[k]); m = fmaxf(m, att[k]); }
    float ssum = 0.f;
    #pragma unroll
    for (int k=0;k<9;k++){ att[k] = __expf(att[k]-m); ssum += att[k]; }
    float inv = 1.f/ssum;

    v2f acc2[8];
    #pragma unroll
    for (int j=0;j<8;j++) acc2[j] = (v2f){0.f, 0.f};
    int chbase = g*GCn + half*16;
    const bf16* xb = P + ((((size_t)b) << 14))*Cn + chbase;
    #pragma unroll
    for (int k=0;k<9;k++){
        unsigned opair = ofp[k];
        float ph = (float)(h + k/3 - 1) + 0.1f*lo16(opair);
        float pw = (float)(w + k%3 - 1) + 0.1f*hi16(opair);
        ph = fminf(fmaxf(ph, 0.f), 127.f);
        pw = fminf(fmaxf(pw, 0.f), 127.f);
        int hf = (int)ph, wf = (int)pw;
        float fh = ph - (float)hf, fw = pw - (float)wf;
        int hc = min(hf+1,127), wc = min(wf+1,127);
        float a = att[k]*inv;
        float w00=(1.f-fh)*(1.f-fw)*a, w01=(1.f-fh)*fw*a, w10=fh*(1.f-fw)*a, w11=fh*fw*a;
        const uint4* p00 = (const uint4*)(xb + ((hf<<7)+wf)*Cn);
        const uint4* p01 = (const uint4*)(xb + ((hf<<7)+wc)*Cn);
        const uint4* p10 = (const uint4*)(xb + ((hc<<7)+wf)*Cn);
        const uint4* p11 = (const uint4*)(xb + ((hc<<7)+wc)*Cn);
        #pragma unroll
        for (int cs=0;cs<2;cs++){
            uint4 a00=p00[cs], a01=p01[cs], a10=p10[cs], a11=p11[cs];
            unsigned u00[4]={a00.x,a00.y,a00.z,a00.w};
            unsigned u01[4]={a01.x,a01.y,a01.z,a01.w};
            unsigned u10[4]={a10.x,a10.y,a10.z,a10.w};
            unsigned u11[4]={a11.x,a11.y,a11.z,a11.w};
            #pragma unroll
            for (int t=0;t<4;t++)
                acc2[cs*4+t] += up2(u00[t])*w00 + up2(u01[t])*w01
                              + up2(u10[t])*w10 + up2(u11[t])*w11;
        }
    }
    bf16 ov[16];
    #pragma unroll
    for (int j=0;j<8;j++){
        ov[2*j]   = __float2bfloat16(acc2[j].x);
        ov[2*j+1] = __float2bfloat16(acc2[j].y);
    }
    uint4* sp = (uint4*)(S + (size_t)pix*Cn + chbase);
    sp[0] = ((uint4*)ov)[0];
    sp[1] = ((uint4*)ov)[1];
}

extern "C" void kernel_launch(void* const* d_in, const int* in_sizes, int n_in,
                              void* d_out, int out_size, void* d_ws, size_t ws_size,
                              hipStream_t stream)
{
    const float* x      = (const float*)d_in[0];
    const float* w_in   = (const float*)d_in[1];
    const float* b_in   = (const float*)d_in[2];
    const float* w_dw   = (const float*)d_in[3];
    const float* b_dw   = (const float*)d_in[4];
    const float* w_pw   = (const float*)d_in[5];
    const float* b_pw   = (const float*)d_in[6];
    const float* w_off  = (const float*)d_in[7];
    const float* b_off  = (const float*)d_in[8];
    const float* w_mask = (const float*)d_in[9];
    const float* b_mask = (const float*)d_in[10];
    const float* w_out  = (const float*)d_in[11];
    const float* b_out  = (const float*)d_in[12];
    float* out = (float*)d_out;

    char* ws = (char*)d_ws;
    size_t off = 0;
    auto carve = [&](size_t bytes)->char* {
        char* p = ws + off; off += (bytes + 255) & ~(size_t)255; return p; };
    bf16* XB  = (bf16*)carve((size_t)NPIX*Cn*2);   // bf16 x; later reused as X2
    bf16* P   = (bf16*)carve((size_t)NPIX*Cn*2);   // x_proj
    bf16* D   = (bf16*)carve((size_t)NPIX*Cn*2);   // dw out, later reused as sampled S
    bf16* OM  = (bf16*)carve((size_t)NPIX*162*2);  // offsets|mask logits
    bf16* wfI = (bf16*)carve(36864*2);
    bf16* wfP = (bf16*)carve(36864*2);
    bf16* wfO = (bf16*)carve(36864*2);
    bf16* wfM = (bf16*)carve(36864*2);
    float* bM = (float*)carve(192*4);
    bf16* WDW = (bf16*)carve(1728*2);

    dim3 blk(256);
    cvt_bf16<<<12288, blk, 0, stream>>>(x, XB, (long)NPIX*Cn);
    cvt_bf16<<<1,     blk, 0, stream>>>(w_dw, WDW, 1728);
    swizzle_w<<<144, blk, 0, stream>>>(w_in,  wfI, 192);
    swizzle_w<<<144, blk, 0, stream>>>(w_pw,  wfP, 192);
    swizzle_w<<<144, blk, 0, stream>>>(w_out, wfO, 192);
    swizzle_om<<<144, blk, 0, stream>>>(w_off, w_mask, b_off, b_mask, wfM, bM);

    dim3 ggrid(512, 2);
    gemm6r<bf16><<<ggrid, blk, 0, stream>>>(XB, (const v8s*)wfI, b_in, P, 192, 192);

    dw_silu<<<6144, blk, 0, stream>>>(XB, WDW, b_dw, D);

    // XB dead now; reuse as X2
    bf16* X2 = XB;
    gemm6r<bf16><<<ggrid, blk, 0, stream>>>(D,  (const v8s*)wfP, b_pw, X2, 192, 192);
    gemm6r<bf16><<<ggrid, blk, 0, stream>>>(X2, (const v8s*)wfM, bM,  OM, 162, 162);

    deform_sample<<<6144, blk, 0, stream>>>(P, OM, D);   // S overwrites D

    gemm6r<float><<<ggrid, blk, 0, stream>>>(D, (const v8s*)wfO, b_out, out, 192, 192);
}